// Round 2
// baseline (223.730 us; speedup 1.0000x reference)
//
#include <hip/hip_runtime.h>
#include <hip/hip_bf16.h>

#define S 4096
#define D 256
#define NB 4

typedef __attribute__((ext_vector_type(8))) __bf16 bf16x8;
typedef __attribute__((ext_vector_type(8))) short s16x8;
typedef __attribute__((ext_vector_type(4))) short s16x4;
typedef __attribute__((ext_vector_type(4))) float f32x4;
typedef __attribute__((ext_vector_type(8))) _Float16 h16x8;

#define MFMA(a, b, c) __builtin_amdgcn_mfma_f32_16x16x32_bf16(a, b, c, 0, 0, 0)
#define MFMA8(a, b, c) __builtin_amdgcn_mfma_f32_16x16x32_fp8_fp8(a, b, c, 0, 0, 0)

__device__ __forceinline__ short f2bf(float f) {
    union { float f; unsigned u; } v; v.f = f;
    unsigned r = v.u + 0x7fffu + ((v.u >> 16) & 1u);   // RNE
    return (short)(r >> 16);
}

// native cast -> v_cvt_pk_bf16_f32 on gfx950 (RNE)
__device__ __forceinline__ short f2bf_hw(float f) {
    __bf16 h = (__bf16)f;
    return __builtin_bit_cast(short, h);
}

__device__ __forceinline__ void g2lds16(const char* g, char* l) {
    __builtin_amdgcn_global_load_lds(
        (const __attribute__((address_space(1))) unsigned int*)g,
        (__attribute__((address_space(3))) unsigned int*)l, 16, 0, 0);
}

// ---------------- prep: x -> fp8(XOR-swizzled) + bf16 x^T + row norms; W -> bf16 ----------------
__global__ __launch_bounds__(256) void k_prep(const float* __restrict__ x,
                                              const float* __restrict__ Wv,
                                              unsigned char* __restrict__ xb8,
                                              short* __restrict__ xt,
                                              short* __restrict__ wb,
                                              float* __restrict__ sqg) {
    const int tid = threadIdx.x;
    if (blockIdx.x >= 512) {   // W fp32 -> bf16
        int idx = (((int)blockIdx.x - 512) * 256 + tid) * 16;
        #pragma unroll
        for (int h = 0; h < 2; h++) {
            float4 f0 = *(const float4*)(Wv + idx + h * 8);
            float4 f1 = *(const float4*)(Wv + idx + h * 8 + 4);
            s16x8 o;
            o[0] = f2bf(f0.x); o[1] = f2bf(f0.y); o[2] = f2bf(f0.z); o[3] = f2bf(f0.w);
            o[4] = f2bf(f1.x); o[5] = f2bf(f1.y); o[6] = f2bf(f1.z); o[7] = f2bf(f1.w);
            *(s16x8*)(wb + idx + h * 8) = o;
        }
        return;
    }

    __shared__ short sX[32 * 264];
    const int b = blockIdx.x >> 7, s0 = (blockIdx.x & 127) * 32;
    const int row = tid >> 3, c8 = tid & 7;
    {
        const float* src = x + (size_t)(b * S + s0 + row) * D + c8 * 32;
        unsigned char* xrow = xb8 + (size_t)(b * S + s0 + row) * D;
        float ss = 0.f;
        int p8[8];
        #pragma unroll
        for (int j = 0; j < 8; j++) {
            float4 v = ((const float4*)src)[j];
            ss += v.x * v.x + v.y * v.y + v.z * v.z + v.w * v.w;
            s16x4 o;
            o.x = f2bf(v.x); o.y = f2bf(v.y); o.z = f2bf(v.z); o.w = f2bf(v.w);
            *(s16x4*)(sX + row * 264 + c8 * 32 + j * 4) = o;
            int pk = __builtin_amdgcn_cvt_pk_fp8_f32(v.x, v.y, 0, false);
            p8[j] = __builtin_amdgcn_cvt_pk_fp8_f32(v.z, v.w, pk, true);
        }
        ss += __shfl_xor(ss, 1, 64);
        ss += __shfl_xor(ss, 2, 64);
        ss += __shfl_xor(ss, 4, 64);
        int4 lo = {p8[0], p8[1], p8[2], p8[3]};
        int4 hi = {p8[4], p8[5], p8[6], p8[7]};
        *(int4*)(xrow + (((2 * c8) ^ (row & 7)) << 4)) = lo;
        *(int4*)(xrow + (((2 * c8 + 1) ^ (row & 7)) << 4)) = hi;
        if (c8 == 0) sqg[b * S + s0 + row] = ss;
    }
    __syncthreads();
    {
        short tmp[32];
        #pragma unroll
        for (int s = 0; s < 32; s++) tmp[s] = sX[s * 264 + tid];
        short* dst = xt + (size_t)(b * D + tid) * S + s0;
        #pragma unroll
        for (int i = 0; i < 4; i++)
            *(s16x8*)(dst + i * 8) = *(const s16x8*)(tmp + i * 8);
    }
}

// ---------------- Main fused attention ----------------
// 256 threads = 4 waves. q-tile 64, t-tile 32. Gram fp8 SWAPPED (A = t-tile from LDS,
// B = xq regs) so each lane owns one q-column: sK writes become ds_write_b64, rowsum is
// one scalar/lane. PV(prev) issued between Gram and Cauchy to keep matrix pipe fed.
// __launch_bounds__(256,3): cap combined VGPR+AGPR <=170 -> 3 blocks/CU.
template <int TSPLIT>
__global__ __launch_bounds__(256, 3) void k_attn(const unsigned char* __restrict__ xb8,
                                                 const short* __restrict__ xt,
                                                 const float* __restrict__ sq,
                                                 const float* __restrict__ logt,
                                                 _Float16* __restrict__ pex,
                                                 float* __restrict__ rws) {
    __shared__ char sXt[2][32 * 256];
    __shared__ short sK[2][64 * 36];

    const int tid = threadIdx.x;
    const int w = tid >> 6, lane = tid & 63;
    const int col = lane & 15, quad = lane >> 4;
    const int cx = col & 7;

    constexpr int LT = (TSPLIT == 4) ? 2 : 1;
    const int th = blockIdx.x & (TSPLIT - 1);
    const int b  = (blockIdx.x >> LT) & 3;
    const int qt = blockIdx.x >> (LT + 2);
    const int q0 = qt * 64;
    const int t_base = th * (S / TSPLIT);
    const int NT = (S / TSPLIT) / 32;

    float temp = fmaxf(__expf(logt[0]), 1e-5f);
    float t2 = temp * temp;
    float t2inv = __builtin_amdgcn_rcpf(t2);

    const unsigned char* xtb = xb8 + (size_t)b * S * D;
    const short* vtb = xt + (size_t)b * D * S;
    const float* sqb = sq + b * S;

    long xq[8];
    {
        const unsigned char* xrow = xtb + (size_t)(q0 + w * 16 + col) * D;
        #pragma unroll
        for (int ks = 0; ks < 8; ks++)
            xq[ks] = *(const long*)(xrow + (((ks * 2 + (quad >> 1)) ^ cx) << 4) + (quad & 1) * 8);
    }
    const int gq = q0 + w * 16 + col;       // this lane's q (after operand swap)
    const float stq = sqb[gq] + t2;         // hoisted: t2 + ||x_q||^2

    f32x4 acc[4][4];
    #pragma unroll
    for (int mi = 0; mi < 4; mi++)
        #pragma unroll
        for (int ni = 0; ni < 4; ni++)
            acc[mi][ni] = (f32x4){0.f, 0.f, 0.f, 0.f};
    float rs = 0.f;

    {   // prologue: async-stage tile 0
        const char* g = (const char*)(xtb + (size_t)t_base * D);
        #pragma unroll
        for (int p = 0; p < 2; p++) {
            int c = p * 256 + tid;
            g2lds16(g + c * 16, &sXt[0][c * 16]);
        }
    }

    for (int i = 0; i < NT; i++) {
        const int t0 = t_base + i * 32;
        const int cur = i & 1;
        __syncthreads();

        if (i + 1 < NT) {
            const char* g = (const char*)(xtb + (size_t)(t0 + 32) * D);
            #pragma unroll
            for (int p = 0; p < 2; p++) {
                int c = p * 256 + tid;
                g2lds16(g + c * 16, &sXt[cur ^ 1][c * 16]);
            }
        }

        bf16x8 vb[4];
        if (i > 0) {
            const int tp = t0 - 32;
            #pragma unroll
            for (int ni = 0; ni < 4; ni++)
                vb[ni] = *(const bf16x8*)(vtb + (size_t)(w * 64 + ni * 16 + col) * S + tp + quad * 8);
        }

        // Gram (swapped): A = t-tile rows from LDS, B = xq. Lane -> (q=col, t=quad*4+rr).
        f32x4 p2v[2];
        p2v[0] = (f32x4){0.f, 0.f, 0.f, 0.f};
        p2v[1] = (f32x4){0.f, 0.f, 0.f, 0.f};
        #pragma unroll
        for (int ks = 0; ks < 8; ks++) {
            int co = (((ks * 2 + (quad >> 1)) ^ cx) << 4) + (quad & 1) * 8;
            long a0 = *(const long*)(&sXt[cur][col * 256 + co]);
            long a1 = *(const long*)(&sXt[cur][(col + 16) * 256 + co]);
            p2v[0] = MFMA8(a0, xq[ks], p2v[0]);
            p2v[1] = MFMA8(a1, xq[ks], p2v[1]);
        }

        // PV for PREVIOUS tile: independent of p2v -> overlaps the Cauchy wait.
        if (i > 0) {
            __builtin_amdgcn_s_setprio(1);
            #pragma unroll
            for (int mi = 0; mi < 4; mi++) {
                bf16x8 af = *(const bf16x8*)(&sK[cur ^ 1][(mi * 16 + col) * 36 + quad * 8]);
                #pragma unroll
                for (int ni = 0; ni < 4; ni++)
                    acc[mi][ni] = MFMA(af, vb[ni], acc[mi][ni]);
            }
            __builtin_amdgcn_s_setprio(0);
        }

        // Cauchy elementwise: u = 1/max(t2 + d2raw, t2); lane owns q=gq, t runs over 8.
        {
            f32x4 sqt0 = *(const f32x4*)(sqb + t0 + quad * 4);
            f32x4 sqt1 = *(const f32x4*)(sqb + t0 + 16 + quad * 4);
            const bool dg = ((unsigned)(t0 - q0) < 64u);
            const int qmt = gq - t0;   // diag when qmt == tf*16 + quad*4 + rr
            #pragma unroll
            for (int tf = 0; tf < 2; tf++) {
                f32x4 sqt = tf ? sqt1 : sqt0;
                s16x4 pk;
                if (dg) {
                    #pragma unroll
                    for (int rr = 0; rr < 4; rr++) {
                        float d = fmaxf(stq + sqt[rr] - 2.f * p2v[tf][rr], t2);
                        float u = __builtin_amdgcn_rcpf(d);
                        if (qmt == tf * 16 + quad * 4 + rr) u = t2inv;   // exact diagonal
                        rs += u;
                        pk[rr] = f2bf_hw(u);
                    }
                } else {
                    #pragma unroll
                    for (int rr = 0; rr < 4; rr++) {
                        float d = fmaxf(stq + sqt[rr] - 2.f * p2v[tf][rr], t2);
                        float u = __builtin_amdgcn_rcpf(d);
                        rs += u;
                        pk[rr] = f2bf_hw(u);
                    }
                }
                *(s16x4*)(&sK[cur][(w * 16 + col) * 36 + tf * 16 + quad * 4]) = pk;
            }
        }
    }

    __syncthreads();
    {   // final PV
        const int tp = t_base + (NT - 1) * 32;
        const int cur = (NT - 1) & 1;
        bf16x8 vb[4];
        #pragma unroll
        for (int ni = 0; ni < 4; ni++)
            vb[ni] = *(const bf16x8*)(vtb + (size_t)(w * 64 + ni * 16 + col) * S + tp + quad * 8);
        #pragma unroll
        for (int mi = 0; mi < 4; mi++) {
            bf16x8 af = *(const bf16x8*)(&sK[cur][(mi * 16 + col) * 36 + quad * 8]);
            #pragma unroll
            for (int ni = 0; ni < 4; ni++)
                acc[mi][ni] = MFMA(af, vb[ni], acc[mi][ni]);
        }
    }

    // rowsum: lane owns q=gq; reduce across quads only.
    rs += __shfl_xor(rs, 16, 64);
    rs += __shfl_xor(rs, 32, 64);
    if (quad == 0) rws[(size_t)th * NB * S + b * S + gq] = rs;

    _Float16* ob = pex + (size_t)th * NB * S * D + (size_t)(b * S + q0) * D;
    #pragma unroll
    for (int mi = 0; mi < 4; mi++)
        #pragma unroll
        for (int rr = 0; rr < 4; rr++)
            #pragma unroll
            for (int ni = 0; ni < 4; ni++)
                ob[(size_t)(mi * 16 + quad * 4 + rr) * D + w * 64 + ni * 16 + col] =
                    (_Float16)acc[mi][ni][rr];
}

// ---------------- post: out = (sum(Yp)/sum(rp)) @ W^T + b ----------------
template <int NP>
__global__ __launch_bounds__(256) void k_post(const _Float16* __restrict__ pex,
                                              const float* __restrict__ rws,
                                              const short* __restrict__ wb,
                                              const float* __restrict__ bv,
                                              float* __restrict__ out) {
    __shared__ short sY[32 * 264];

    const int tid = threadIdx.x;
    const int w = tid >> 6, lane = tid & 63;
    const int col = lane & 15, quad = lane >> 4;
    const int b = blockIdx.x >> 7, s0 = (blockIdx.x & 127) * 32;

    // W preload (bf16): wf[4][8]
    bf16x8 wf[4][8];
    #pragma unroll
    for (int ni = 0; ni < 4; ni++)
        #pragma unroll
        for (int ks = 0; ks < 8; ks++)
            wf[ni][ks] = *(const bf16x8*)(wb + (size_t)(w * 64 + ni * 16 + col) * D + ks * 32 + quad * 8);

    {   // load partials, normalize, stage bf16
        const int row = tid >> 3, c8 = tid & 7;
        const int gs = b * S + s0 + row;
        float rsum = rws[gs];
        #pragma unroll
        for (int p = 1; p < NP; p++) rsum += rws[(size_t)p * NB * S + gs];
        float rinv = __builtin_amdgcn_rcpf(fmaxf(rsum, 1e-8f));
        const _Float16* y0 = pex + (size_t)gs * D + c8 * 32;
        #pragma unroll
        for (int j = 0; j < 4; j++) {
            float f[8] = {0.f, 0.f, 0.f, 0.f, 0.f, 0.f, 0.f, 0.f};
            #pragma unroll
            for (int p = 0; p < NP; p++) {
                h16x8 a = *(const h16x8*)(y0 + (size_t)p * NB * S * D + j * 8);
                #pragma unroll
                for (int e = 0; e < 8; e++) f[e] += (float)a[e];
            }
            s16x8 o;
            #pragma unroll
            for (int e = 0; e < 8; e++) o[e] = f2bf_hw(f[e] * rinv);
            *(s16x8*)(sY + row * 264 + c8 * 32 + j * 8) = o;
        }
    }
    __syncthreads();

    f32x4 acc[2][4];
    #pragma unroll
    for (int mi = 0; mi < 2; mi++)
        #pragma unroll
        for (int ni = 0; ni < 4; ni++)
            acc[mi][ni] = (f32x4){0.f, 0.f, 0.f, 0.f};

    #pragma unroll
    for (int ks = 0; ks < 8; ks++) {
        bf16x8 a[2];
        #pragma unroll
        for (int mi = 0; mi < 2; mi++)
            a[mi] = *(const bf16x8*)(sY + (mi * 16 + col) * 264 + ks * 32 + quad * 8);
        #pragma unroll
        for (int mi = 0; mi < 2; mi++)
            #pragma unroll
            for (int ni = 0; ni < 4; ni++)
                acc[mi][ni] = MFMA(a[mi], wf[ni][ks], acc[mi][ni]);
    }

    float* ob = out + (size_t)(b * S + s0) * D;
    #pragma unroll
    for (int ni = 0; ni < 4; ni++) {
        int d = w * 64 + ni * 16 + col;
        float bvv = bv[d];
        #pragma unroll
        for (int mi = 0; mi < 2; mi++)
            #pragma unroll
            for (int r = 0; r < 4; r++)
                ob[(size_t)(mi * 16 + quad * 4 + r) * D + d] = acc[mi][ni][r] + bvv;
    }
}

extern "C" void kernel_launch(void* const* d_in, const int* in_sizes, int n_in,
                              void* d_out, int out_size, void* d_ws, size_t ws_size,
                              hipStream_t stream) {
    const float* x    = (const float*)d_in[0];
    const float* Wv   = (const float*)d_in[1];
    const float* bv   = (const float*)d_in[2];
    const float* logt = (const float*)d_in[3];
    float* out = (float*)d_out;

    char* ws = (char*)d_ws;
    unsigned char* xb8 = (unsigned char*)ws;          // fp8 x (swizzled) [B][S][D]   4 MB
    short* xt  = (short*)(ws + 4194304);              // bf16 x^T [B][D][S]           8 MB
    short* wb  = (short*)(ws + 12582912);              // bf16 W [D][D]                128 KB
    float* sq  = (float*)(ws + 12713984);              // ||x||^2 [B][S]               64 KB
    float* rws = (float*)(ws + 12779520);              // rowsums [<=4][B][S]          256 KB
    _Float16* pex = (_Float16*)(ws + 13041664);        // fp16 Y partials [<=4][B][S][D]

    k_prep<<<528, 256, 0, stream>>>(x, Wv, xb8, xt, wb, sq);

    const size_t need4 = 13041664ull + 4ull * NB * S * D * 2;   // ~46.6 MB
    if (ws_size >= need4) {
        k_attn<4><<<NB * (S / 64) * 4, 256, 0, stream>>>(xb8, xt, sq, logt, pex, rws);
        k_post<4><<<NB * (S / 32), 256, 0, stream>>>(pex, rws, wb, bv, out);
    } else {
        k_attn<2><<<NB * (S / 64) * 2, 256, 0, stream>>>(xb8, xt, sq, logt, pex, rws);
        k_post<2><<<NB * (S / 32), 256, 0, stream>>>(pex, rws, wb, bv, out);
    }
}

// Round 3
// 191.472 us; speedup vs baseline: 1.1685x; 1.1685x over previous
//
#include <hip/hip_runtime.h>
#include <hip/hip_bf16.h>

#define S 4096
#define D 256
#define NB 4

typedef __attribute__((ext_vector_type(8))) __bf16 bf16x8;
typedef __attribute__((ext_vector_type(8))) short s16x8;
typedef __attribute__((ext_vector_type(4))) short s16x4;
typedef __attribute__((ext_vector_type(4))) float f32x4;
typedef __attribute__((ext_vector_type(8))) _Float16 h16x8;

#define MFMA(a, b, c) __builtin_amdgcn_mfma_f32_16x16x32_bf16(a, b, c, 0, 0, 0)
#define MFMA8(a, b, c) __builtin_amdgcn_mfma_f32_16x16x32_fp8_fp8(a, b, c, 0, 0, 0)

__device__ __forceinline__ short f2bf(float f) {
    union { float f; unsigned u; } v; v.f = f;
    unsigned r = v.u + 0x7fffu + ((v.u >> 16) & 1u);   // RNE
    return (short)(r >> 16);
}

// native cast -> v_cvt_pk_bf16_f32 on gfx950 (RNE)
__device__ __forceinline__ short f2bf_hw(float f) {
    __bf16 h = (__bf16)f;
    return __builtin_bit_cast(short, h);
}

__device__ __forceinline__ void g2lds16(const char* g, char* l) {
    __builtin_amdgcn_global_load_lds(
        (const __attribute__((address_space(1))) unsigned int*)g,
        (__attribute__((address_space(3))) unsigned int*)l, 16, 0, 0);
}

// ---------------- prep: x -> fp8(XOR-swizzled) + bf16 x^T + row norms; W -> bf16 ----------------
__global__ __launch_bounds__(256) void k_prep(const float* __restrict__ x,
                                              const float* __restrict__ Wv,
                                              unsigned char* __restrict__ xb8,
                                              short* __restrict__ xt,
                                              short* __restrict__ wb,
                                              float* __restrict__ sqg) {
    const int tid = threadIdx.x;
    if (blockIdx.x >= 512) {   // W fp32 -> bf16
        int idx = (((int)blockIdx.x - 512) * 256 + tid) * 16;
        #pragma unroll
        for (int h = 0; h < 2; h++) {
            float4 f0 = *(const float4*)(Wv + idx + h * 8);
            float4 f1 = *(const float4*)(Wv + idx + h * 8 + 4);
            s16x8 o;
            o[0] = f2bf(f0.x); o[1] = f2bf(f0.y); o[2] = f2bf(f0.z); o[3] = f2bf(f0.w);
            o[4] = f2bf(f1.x); o[5] = f2bf(f1.y); o[6] = f2bf(f1.z); o[7] = f2bf(f1.w);
            *(s16x8*)(wb + idx + h * 8) = o;
        }
        return;
    }

    __shared__ short sX[32 * 264];
    const int b = blockIdx.x >> 7, s0 = (blockIdx.x & 127) * 32;
    const int row = tid >> 3, c8 = tid & 7;
    {
        const float* src = x + (size_t)(b * S + s0 + row) * D + c8 * 32;
        unsigned char* xrow = xb8 + (size_t)(b * S + s0 + row) * D;
        float ss = 0.f;
        int p8[8];
        #pragma unroll
        for (int j = 0; j < 8; j++) {
            float4 v = ((const float4*)src)[j];
            ss += v.x * v.x + v.y * v.y + v.z * v.z + v.w * v.w;
            s16x4 o;
            o.x = f2bf(v.x); o.y = f2bf(v.y); o.z = f2bf(v.z); o.w = f2bf(v.w);
            *(s16x4*)(sX + row * 264 + c8 * 32 + j * 4) = o;
            int pk = __builtin_amdgcn_cvt_pk_fp8_f32(v.x, v.y, 0, false);
            p8[j] = __builtin_amdgcn_cvt_pk_fp8_f32(v.z, v.w, pk, true);
        }
        ss += __shfl_xor(ss, 1, 64);
        ss += __shfl_xor(ss, 2, 64);
        ss += __shfl_xor(ss, 4, 64);
        int4 lo = {p8[0], p8[1], p8[2], p8[3]};
        int4 hi = {p8[4], p8[5], p8[6], p8[7]};
        *(int4*)(xrow + (((2 * c8) ^ (row & 7)) << 4)) = lo;
        *(int4*)(xrow + (((2 * c8 + 1) ^ (row & 7)) << 4)) = hi;
        if (c8 == 0) sqg[b * S + s0 + row] = ss;
    }
    __syncthreads();
    {
        short tmp[32];
        #pragma unroll
        for (int s = 0; s < 32; s++) tmp[s] = sX[s * 264 + tid];
        short* dst = xt + (size_t)(b * D + tid) * S + s0;
        #pragma unroll
        for (int i = 0; i < 4; i++)
            *(s16x8*)(dst + i * 8) = *(const s16x8*)(tmp + i * 8);
    }
}

// ---------------- Main fused attention ----------------
// 256 threads = 4 waves. q-tile 64, t-tile 32. Gram fp8 SWAPPED (A = t-tile from LDS,
// B = xq regs) -> lane owns one q-column. sK SINGLE-buffered (4.6 KB) with PV in the
// SAME iteration after a raw lgkm-only mid-barrier (stage loads stay in flight).
// LDS total 20992 B -> target 3 blocks/CU. No launch_bounds waves cap (round-2 spill lesson).
template <int TSPLIT>
__global__ __launch_bounds__(256) void k_attn(const unsigned char* __restrict__ xb8,
                                              const short* __restrict__ xt,
                                              const float* __restrict__ sq,
                                              const float* __restrict__ logt,
                                              _Float16* __restrict__ pex,
                                              float* __restrict__ rws) {
    __shared__ char sXt[2][32 * 256];   // 16384 B
    __shared__ short sK[64 * 36];       //  4608 B  (single buffer)

    const int tid = threadIdx.x;
    const int w = tid >> 6, lane = tid & 63;
    const int col = lane & 15, quad = lane >> 4;
    const int cx = col & 7;

    constexpr int LT = (TSPLIT == 4) ? 2 : 1;
    const int th = blockIdx.x & (TSPLIT - 1);
    const int b  = (blockIdx.x >> LT) & 3;
    const int qt = blockIdx.x >> (LT + 2);
    const int q0 = qt * 64;
    const int t_base = th * (S / TSPLIT);
    const int NT = (S / TSPLIT) / 32;

    float temp = fmaxf(__expf(logt[0]), 1e-5f);
    float t2 = temp * temp;
    float t2inv = __builtin_amdgcn_rcpf(t2);

    const unsigned char* xtb = xb8 + (size_t)b * S * D;
    const short* vtb = xt + (size_t)b * D * S;
    const float* sqb = sq + b * S;

    long xq[8];
    {
        const unsigned char* xrow = xtb + (size_t)(q0 + w * 16 + col) * D;
        #pragma unroll
        for (int ks = 0; ks < 8; ks++)
            xq[ks] = *(const long*)(xrow + (((ks * 2 + (quad >> 1)) ^ cx) << 4) + (quad & 1) * 8);
    }
    const int gq = q0 + w * 16 + col;       // this lane's q (after operand swap)
    const float stq = sqb[gq] + t2;         // hoisted: t2 + ||x_q||^2

    f32x4 acc[4][4];
    #pragma unroll
    for (int mi = 0; mi < 4; mi++)
        #pragma unroll
        for (int ni = 0; ni < 4; ni++)
            acc[mi][ni] = (f32x4){0.f, 0.f, 0.f, 0.f};
    float rs = 0.f;

    {   // prologue: async-stage tile 0
        const char* g = (const char*)(xtb + (size_t)t_base * D);
        #pragma unroll
        for (int p = 0; p < 2; p++) {
            int c = p * 256 + tid;
            g2lds16(g + c * 16, &sXt[0][c * 16]);
        }
    }

    for (int i = 0; i < NT; i++) {
        const int t0 = t_base + i * 32;
        const int cur = i & 1;
        __syncthreads();   // full drain: sXt[cur] staged; sK(prev) fully consumed

        // stage next tile (consumed after NEXT top barrier -> full iteration of hide)
        if (i + 1 < NT) {
            const char* g = (const char*)(xtb + (size_t)(t0 + 32) * D);
            #pragma unroll
            for (int p = 0; p < 2; p++) {
                int c = p * 256 + tid;
                g2lds16(g + c * 16, &sXt[cur ^ 1][c * 16]);
            }
        }

        // V-loads for THIS tile, issued early (consumed in PV after mid-barrier)
        bf16x8 vb[4];
        #pragma unroll
        for (int ni = 0; ni < 4; ni++)
            vb[ni] = *(const bf16x8*)(vtb + (size_t)(w * 64 + ni * 16 + col) * S + t0 + quad * 8);

        // Gram (swapped), 4 independent MFMA chains to halve dep latency.
        f32x4 pa[2], pb[2];
        pa[0] = (f32x4){0.f,0.f,0.f,0.f}; pa[1] = (f32x4){0.f,0.f,0.f,0.f};
        pb[0] = (f32x4){0.f,0.f,0.f,0.f}; pb[1] = (f32x4){0.f,0.f,0.f,0.f};
        #pragma unroll
        for (int ks = 0; ks < 4; ks++) {
            int co0 = (((ks * 2 + (quad >> 1)) ^ cx) << 4) + (quad & 1) * 8;
            int co1 = ((((ks + 4) * 2 + (quad >> 1)) ^ cx) << 4) + (quad & 1) * 8;
            long a0 = *(const long*)(&sXt[cur][col * 256 + co0]);
            long a1 = *(const long*)(&sXt[cur][(col + 16) * 256 + co0]);
            long a2 = *(const long*)(&sXt[cur][col * 256 + co1]);
            long a3 = *(const long*)(&sXt[cur][(col + 16) * 256 + co1]);
            pa[0] = MFMA8(a0, xq[ks], pa[0]);
            pa[1] = MFMA8(a1, xq[ks], pa[1]);
            pb[0] = MFMA8(a2, xq[ks + 4], pb[0]);
            pb[1] = MFMA8(a3, xq[ks + 4], pb[1]);
        }
        f32x4 p2v[2];
        p2v[0] = pa[0] + pb[0];
        p2v[1] = pa[1] + pb[1];

        // Cauchy: u = 1/max(t2 + d2raw, t2); lane owns q=gq, t runs over 8.
        {
            f32x4 sqt0 = *(const f32x4*)(sqb + t0 + quad * 4);
            f32x4 sqt1 = *(const f32x4*)(sqb + t0 + 16 + quad * 4);
            const bool dg = ((unsigned)(t0 - q0) < 64u);
            const int qmt = gq - t0;   // diag when qmt == tf*16 + quad*4 + rr
            #pragma unroll
            for (int tf = 0; tf < 2; tf++) {
                f32x4 sqt = tf ? sqt1 : sqt0;
                s16x4 pk;
                if (dg) {
                    #pragma unroll
                    for (int rr = 0; rr < 4; rr++) {
                        float d = fmaxf(stq + sqt[rr] - 2.f * p2v[tf][rr], t2);
                        float u = __builtin_amdgcn_rcpf(d);
                        if (qmt == tf * 16 + quad * 4 + rr) u = t2inv;   // exact diagonal
                        rs += u;
                        pk[rr] = f2bf_hw(u);
                    }
                } else {
                    #pragma unroll
                    for (int rr = 0; rr < 4; rr++) {
                        float d = fmaxf(stq + sqt[rr] - 2.f * p2v[tf][rr], t2);
                        float u = __builtin_amdgcn_rcpf(d);
                        rs += u;
                        pk[rr] = f2bf_hw(u);
                    }
                }
                *(s16x4*)(&sK[(w * 16 + col) * 36 + tf * 16 + quad * 4]) = pk;
            }
        }

        // mid-barrier: drain ONLY lgkm (sK ds_writes). Stage loads (vmcnt) stay in flight.
        asm volatile("s_waitcnt lgkmcnt(0)" ::: "memory");
        __builtin_amdgcn_s_barrier();
        __builtin_amdgcn_sched_barrier(0);

        // PV: same tile, reads sK across waves + vb regs.
        __builtin_amdgcn_s_setprio(1);
        #pragma unroll
        for (int mi = 0; mi < 4; mi++) {
            bf16x8 af = *(const bf16x8*)(&sK[(mi * 16 + col) * 36 + quad * 8]);
            #pragma unroll
            for (int ni = 0; ni < 4; ni++)
                acc[mi][ni] = MFMA(af, vb[ni], acc[mi][ni]);
        }
        __builtin_amdgcn_s_setprio(0);
    }

    // rowsum: lane owns q=gq; reduce across quads only.
    rs += __shfl_xor(rs, 16, 64);
    rs += __shfl_xor(rs, 32, 64);
    if (quad == 0) rws[(size_t)th * NB * S + b * S + gq] = rs;

    _Float16* ob = pex + (size_t)th * NB * S * D + (size_t)(b * S + q0) * D;
    #pragma unroll
    for (int mi = 0; mi < 4; mi++)
        #pragma unroll
        for (int rr = 0; rr < 4; rr++)
            #pragma unroll
            for (int ni = 0; ni < 4; ni++)
                ob[(size_t)(mi * 16 + quad * 4 + rr) * D + w * 64 + ni * 16 + col] =
                    (_Float16)acc[mi][ni][rr];
}

// ---------------- post: out = (sum(Yp)/sum(rp)) @ W^T + b ----------------
template <int NP>
__global__ __launch_bounds__(256) void k_post(const _Float16* __restrict__ pex,
                                              const float* __restrict__ rws,
                                              const short* __restrict__ wb,
                                              const float* __restrict__ bv,
                                              float* __restrict__ out) {
    __shared__ short sY[32 * 264];

    const int tid = threadIdx.x;
    const int w = tid >> 6, lane = tid & 63;
    const int col = lane & 15, quad = lane >> 4;
    const int b = blockIdx.x >> 7, s0 = (blockIdx.x & 127) * 32;

    // W preload (bf16): wf[4][8]
    bf16x8 wf[4][8];
    #pragma unroll
    for (int ni = 0; ni < 4; ni++)
        #pragma unroll
        for (int ks = 0; ks < 8; ks++)
            wf[ni][ks] = *(const bf16x8*)(wb + (size_t)(w * 64 + ni * 16 + col) * D + ks * 32 + quad * 8);

    {   // load partials, normalize, stage bf16
        const int row = tid >> 3, c8 = tid & 7;
        const int gs = b * S + s0 + row;
        float rsum = rws[gs];
        #pragma unroll
        for (int p = 1; p < NP; p++) rsum += rws[(size_t)p * NB * S + gs];
        float rinv = __builtin_amdgcn_rcpf(fmaxf(rsum, 1e-8f));
        const _Float16* y0 = pex + (size_t)gs * D + c8 * 32;
        #pragma unroll
        for (int j = 0; j < 4; j++) {
            float f[8] = {0.f, 0.f, 0.f, 0.f, 0.f, 0.f, 0.f, 0.f};
            #pragma unroll
            for (int p = 0; p < NP; p++) {
                h16x8 a = *(const h16x8*)(y0 + (size_t)p * NB * S * D + j * 8);
                #pragma unroll
                for (int e = 0; e < 8; e++) f[e] += (float)a[e];
            }
            s16x8 o;
            #pragma unroll
            for (int e = 0; e < 8; e++) o[e] = f2bf_hw(f[e] * rinv);
            *(s16x8*)(sY + row * 264 + c8 * 32 + j * 8) = o;
        }
    }
    __syncthreads();

    f32x4 acc[2][4];
    #pragma unroll
    for (int mi = 0; mi < 2; mi++)
        #pragma unroll
        for (int ni = 0; ni < 4; ni++)
            acc[mi][ni] = (f32x4){0.f, 0.f, 0.f, 0.f};

    #pragma unroll
    for (int ks = 0; ks < 8; ks++) {
        bf16x8 a[2];
        #pragma unroll
        for (int mi = 0; mi < 2; mi++)
            a[mi] = *(const bf16x8*)(sY + (mi * 16 + col) * 264 + ks * 32 + quad * 8);
        #pragma unroll
        for (int mi = 0; mi < 2; mi++)
            #pragma unroll
            for (int ni = 0; ni < 4; ni++)
                acc[mi][ni] = MFMA(a[mi], wf[ni][ks], acc[mi][ni]);
    }

    float* ob = out + (size_t)(b * S + s0) * D;
    #pragma unroll
    for (int ni = 0; ni < 4; ni++) {
        int d = w * 64 + ni * 16 + col;
        float bvv = bv[d];
        #pragma unroll
        for (int mi = 0; mi < 2; mi++)
            #pragma unroll
            for (int r = 0; r < 4; r++)
                ob[(size_t)(mi * 16 + quad * 4 + r) * D + d] = acc[mi][ni][r] + bvv;
    }
}

extern "C" void kernel_launch(void* const* d_in, const int* in_sizes, int n_in,
                              void* d_out, int out_size, void* d_ws, size_t ws_size,
                              hipStream_t stream) {
    const float* x    = (const float*)d_in[0];
    const float* Wv   = (const float*)d_in[1];
    const float* bv   = (const float*)d_in[2];
    const float* logt = (const float*)d_in[3];
    float* out = (float*)d_out;

    char* ws = (char*)d_ws;
    unsigned char* xb8 = (unsigned char*)ws;          // fp8 x (swizzled) [B][S][D]   4 MB
    short* xt  = (short*)(ws + 4194304);              // bf16 x^T [B][D][S]           8 MB
    short* wb  = (short*)(ws + 12582912);             // bf16 W [D][D]                128 KB
    float* sq  = (float*)(ws + 12713984);             // ||x||^2 [B][S]               64 KB
    float* rws = (float*)(ws + 12779520);             // rowsums [<=4][B][S]          256 KB
    _Float16* pex = (_Float16*)(ws + 13041664);       // fp16 Y partials [<=4][B][S][D]

    k_prep<<<528, 256, 0, stream>>>(x, Wv, xb8, xt, wb, sq);

    const size_t need4 = 13041664ull + 4ull * NB * S * D * 2;   // ~46.6 MB
    if (ws_size >= need4) {
        k_attn<4><<<NB * (S / 64) * 4, 256, 0, stream>>>(xb8, xt, sq, logt, pex, rws);
        k_post<4><<<NB * (S / 32), 256, 0, stream>>>(pex, rws, wb, bv, out);
    } else {
        k_attn<2><<<NB * (S / 64) * 2, 256, 0, stream>>>(xb8, xt, sq, logt, pex, rws);
        k_post<2><<<NB * (S / 32), 256, 0, stream>>>(pex, rws, wb, bv, out);
    }
}